// Round 7
// baseline (59.212 us; speedup 1.0000x reference)
//
#include <hip/hip_runtime.h>
#include <math.h>

#define BATCH 16
#define HH 512
#define WW 512
#define PLANE ((size_t)HH * WW)
#define NELEM ((size_t)BATCH * 3 * PLANE)

// Quant divisor tables, reference's .T applied: QT[u][v] (small ints, exact f32)
__constant__ float QYT[8][8] = {
  {16,12,14,14,18,24,49,72},
  {11,12,13,17,22,35,64,92},
  {10,14,16,22,37,55,78,95},
  {16,19,24,29,56,64,87,98},
  {24,26,40,51,68,81,103,112},
  {40,58,57,87,109,104,121,100},
  {51,60,69,80,103,113,120,103},
  {61,55,56,62,77,92,101,99},
};
__constant__ float QCT[8][8] = {
  {17,18,24,47,99,99,99,99},
  {18,21,26,66,99,99,99,99},
  {24,26,56,99,99,99,99,99},
  {47,66,99,99,99,99,99,99},
  {99,99,99,99,99,99,99,99},
  {99,99,99,99,99,99,99,99},
  {99,99,99,99,99,99,99,99},
  {99,99,99,99,99,99,99,99},
};

// 32x32-pixel tile per 128-thread WG. Grid = 16 images * 256 tiles = 4096 WGs
// (16 WG/CU -> 32 waves/CU resident; LDS 6.5KB, VGPR ~52 both permit it).
// Blocked LDS: Blk[bk][68]; bk 0..15 = Y (4x4 grid), 16..19 = Cb, 20..23 = Cr.
extern "C" __global__ __launch_bounds__(128)
void diffjpeg_kernel(const float* __restrict__ x, const float* __restrict__ src,
                     float* __restrict__ out) {
  __shared__ float Blk[24][68];
  __shared__ float Cs[64];   // Cs[a*8+b] = f32 _COS[a][b] (numpy bit-match)

  const int blk = blockIdx.x;
  const int b   = blk >> 8;          // image 0..15
  const int t   = blk & 255;         // tile (16 rows x 16 cols of 32x32 tiles)
  const int trow = t >> 4, tcol = t & 15;
  const int row0 = trow * 32, col0 = tcol * 32;
  const int tid = threadIdx.x;

  // ---- phase 0: numpy-bitwise cos table ----
  if (tid < 64) {
    int a = tid >> 3, bb = tid & 7;
    float t2 = (float)((2 * a + 1) * bb);
    float t3 = __fmul_rn(t2, 3.14159265358979323846f);
    float t4 = __fmul_rn(t3, 0.0625f);
    Cs[tid] = (float)cos((double)t4);
  }

  const float* Rp = x + (size_t)(b * 3 + 0) * PLANE;
  const float* Gp = x + (size_t)(b * 3 + 1) * PLANE;
  const float* Bp = x + (size_t)(b * 3 + 2) * PLANE;

  // ---- phase 1: x*255 -> sgemm-FMA YCC (+128 chroma) -> 2x2 mean -> -128 ----
  #pragma unroll
  for (int i = 0; i < 2; ++i) {
    int q  = tid + i * 128;          // quad 0..255 (16 rows x 16 cols of 2x2 px)
    int qy = q >> 4, qx = q & 15;
    size_t base = (size_t)(row0 + 2 * qy) * WW + (col0 + 2 * qx);
    float2 r0 = *(const float2*)(Rp + base);
    float2 r1 = *(const float2*)(Rp + base + WW);
    float2 g0 = *(const float2*)(Gp + base);
    float2 g1 = *(const float2*)(Gp + base + WW);
    float2 b0 = *(const float2*)(Bp + base);
    float2 b1 = *(const float2*)(Bp + base + WW);

    float rf[4] = {r0.x, r0.y, r1.x, r1.y};
    float gf[4] = {g0.x, g0.y, g1.x, g1.y};
    float bf[4] = {b0.x, b0.y, b1.x, b1.y};
    float Ym[4], CB[4], CR[4];
    #pragma unroll
    for (int j = 0; j < 4; ++j) {
      float R  = __fmul_rn(rf[j], 255.0f);
      float G  = __fmul_rn(gf[j], 255.0f);
      float Bv = __fmul_rn(bf[j], 255.0f);
      float Yv = __fmaf_rn(Bv, 0.114f, __fmaf_rn(G, 0.587f, __fmul_rn(R, 0.299f)));
      Ym[j] = __fsub_rn(Yv, 128.0f);               // DCT input shift (moved)
      CB[j] = __fadd_rn(
          __fmaf_rn(Bv, 0.5f, __fmaf_rn(G, -0.331264f, __fmul_rn(R, -0.168736f))),
          128.0f);
      CR[j] = __fadd_rn(
          __fmaf_rn(Bv, -0.081312f, __fmaf_rn(G, -0.418688f, __fmul_rn(R, 0.5f))),
          128.0f);
    }

    int ybk = (qy >> 2) * 4 + (qx >> 2);
    int xin = (qy & 3) * 2, yin = (qx & 3) * 2;
    float* Pb = Blk[ybk];
    *(float2*)&Pb[xin * 8 + yin]       = make_float2(Ym[0], Ym[1]);
    *(float2*)&Pb[(xin + 1) * 8 + yin] = make_float2(Ym[2], Ym[3]);

    float sb = __fadd_rn(__fadd_rn(__fadd_rn(CB[0], CB[1]), CB[2]), CB[3]);
    float sr = __fadd_rn(__fadd_rn(__fadd_rn(CR[0], CR[1]), CR[2]), CR[3]);
    // /4.0 == *0.25 exactly (power-of-two scaling, bit-identical)
    int cbk = 16 + (qy >> 3) * 2 + (qx >> 3);
    int coff = (qy & 7) * 8 + (qx & 7);
    Blk[cbk][coff]     = __fsub_rn(__fmul_rn(sb, 0.25f), 128.0f);
    Blk[cbk + 4][coff] = __fsub_rn(__fmul_rn(sr, 0.25f), 128.0f);
  }
  __syncthreads();

  // ---- phase 2: lane owns coefficient (u,v); wave owns 12 blocks ----
  const int w    = tid >> 6;
  const int lane = tid & 63;
  const int u = lane >> 3, v = lane & 7;
  const float au = (u == 0) ? 0.70710678118654746f : 1.0f;
  const float av = (v == 0) ? 0.70710678118654746f : 1.0f;
  const float ao  = __fmul_rn(au, av);        // ALPHA_OUTER[u][v]
  const float sc  = __fmul_rn(ao, 0.25f);     // SCALE[u][v]
  const float qdY = __fmul_rn(QYT[u][v], 0.4f);
  const float qdC = __fmul_rn(QCT[u][v], 0.4f);
  const int  bk0  = w * 12;

  float Wf[64];
  {
    float cu_[8], cv_[8];
    #pragma unroll
    for (int k = 0; k < 8; ++k) { cu_[k] = Cs[k * 8 + u]; cv_[k] = Cs[k * 8 + v]; }
    #pragma unroll
    for (int xx = 0; xx < 8; ++xx)
      #pragma unroll
      for (int yy = 0; yy < 8; ++yy)
        Wf[xx * 8 + yy] = __fmul_rn(cu_[xx], cv_[yy]);  // f32 DCT_T[x][y][u][v]
  }

  // ---- 2a: DCT + quant + diff_round + dequant(*AO), in place ----
  #pragma unroll
  for (int pb = 0; pb < 6; ++pb) {
    int bkA = bk0 + 2 * pb, bkB = bkA + 1;
    const float* A = Blk[bkA];
    const float* C = Blk[bkB];
    float accA = 0.f, accB = 0.f;
    #pragma unroll
    for (int k4 = 0; k4 < 16; ++k4) {
      float4 a = *(const float4*)(A + 4 * k4);   // wave-uniform broadcast
      float4 c = *(const float4*)(C + 4 * k4);
      accA = __fmaf_rn(a.x, Wf[4 * k4 + 0], accA);
      accB = __fmaf_rn(c.x, Wf[4 * k4 + 0], accB);
      accA = __fmaf_rn(a.y, Wf[4 * k4 + 1], accA);
      accB = __fmaf_rn(c.y, Wf[4 * k4 + 1], accB);
      accA = __fmaf_rn(a.z, Wf[4 * k4 + 2], accA);
      accB = __fmaf_rn(c.z, Wf[4 * k4 + 2], accB);
      accA = __fmaf_rn(a.w, Wf[4 * k4 + 3], accA);
      accB = __fmaf_rn(c.w, Wf[4 * k4 + 3], accB);
    }
    float qd = (bkA < 16) ? qdY : qdC;
    float SpA = __fmul_rn(sc, accA);
    float SpB = __fmul_rn(sc, accB);
    float qvA = __fdiv_rn(SpA, qd);
    float qvB = __fdiv_rn(SpB, qd);
    float rA = rintf(qvA), rB = rintf(qvB);
    float dA = __fsub_rn(qvA, rA), dB = __fsub_rn(qvB, rB);
    float eA = __fadd_rn(rA, __fmul_rn(__fmul_rn(dA, dA), dA));
    float eB = __fadd_rn(rB, __fmul_rn(__fmul_rn(dB, dB), dB));
    Blk[bkA][lane] = __fmul_rn(__fmul_rn(eA, qd), ao);  // lane = u*8+v
    Blk[bkB][lane] = __fmul_rn(__fmul_rn(eB, qd), ao);
  }

  // ---- 2b: IDCT (lane owns spatial (u,v)), *0.25, +128, in place ----
  {
    float cu_[8], cv_[8];
    #pragma unroll
    for (int k = 0; k < 8; ++k) { cu_[k] = Cs[u * 8 + k]; cv_[k] = Cs[v * 8 + k]; }
    #pragma unroll
    for (int xx = 0; xx < 8; ++xx)
      #pragma unroll
      for (int yy = 0; yy < 8; ++yy)
        Wf[xx * 8 + yy] = __fmul_rn(cu_[xx], cv_[yy]);  // f32 IDCT_T[x][y][u][v]
  }
  #pragma unroll
  for (int pb = 0; pb < 6; ++pb) {
    int bkA = bk0 + 2 * pb, bkB = bkA + 1;
    const float* A = Blk[bkA];
    const float* C = Blk[bkB];
    float accA = 0.f, accB = 0.f;
    #pragma unroll
    for (int k4 = 0; k4 < 16; ++k4) {
      float4 a = *(const float4*)(A + 4 * k4);
      float4 c = *(const float4*)(C + 4 * k4);
      accA = __fmaf_rn(a.x, Wf[4 * k4 + 0], accA);
      accB = __fmaf_rn(c.x, Wf[4 * k4 + 0], accB);
      accA = __fmaf_rn(a.y, Wf[4 * k4 + 1], accA);
      accB = __fmaf_rn(c.y, Wf[4 * k4 + 1], accB);
      accA = __fmaf_rn(a.z, Wf[4 * k4 + 2], accA);
      accB = __fmaf_rn(c.z, Wf[4 * k4 + 2], accB);
      accA = __fmaf_rn(a.w, Wf[4 * k4 + 3], accA);
      accB = __fmaf_rn(c.w, Wf[4 * k4 + 3], accB);
    }
    Blk[bkA][lane] = __fadd_rn(__fmul_rn(0.25f, accA), 128.0f);
    Blk[bkB][lane] = __fadd_rn(__fmul_rn(0.25f, accB), 128.0f);
  }
  __syncthreads();

  // ---- phase 3: upsample, -128, sgemm-FMA YCC->RGB, clip, /255, store ----
  float* oR = out + (size_t)(b * 3 + 0) * PLANE;
  float* oG = out + (size_t)(b * 3 + 1) * PLANE;
  float* oB = out + (size_t)(b * 3 + 2) * PLANE;
  #pragma unroll
  for (int i = 0; i < 2; ++i) {
    int g = tid + i * 128;           // 32 rows x 8 groups of 4 px
    int py = g >> 3, pxg = g & 7;
    int col = pxg * 4;
    int ybk = (py >> 3) * 4 + (pxg >> 1);
    int yoff = (py & 7) * 8 + (pxg & 1) * 4;
    float4 yv4 = *(const float4*)&Blk[ybk][yoff];
    float yv[4] = {yv4.x, yv4.y, yv4.z, yv4.w};

    int cy = py >> 1, cx = 2 * pxg;
    int cbk = 16 + (cy >> 3) * 2 + (cx >> 3);
    int coff = (cy & 7) * 8 + (cx & 7);
    float2 cbv = *(const float2*)&Blk[cbk][coff];
    float2 crv = *(const float2*)&Blk[cbk + 4][coff];
    float cb0 = __fadd_rn(cbv.x, -128.0f);
    float cb1 = __fadd_rn(cbv.y, -128.0f);
    float cr0 = __fadd_rn(crv.x, -128.0f);
    float cr1 = __fadd_rn(crv.y, -128.0f);
    float cb[4] = {cb0, cb0, cb1, cb1};
    float cr[4] = {cr0, cr0, cr1, cr1};

    float rr[4], gg[4], bb[4];
    #pragma unroll
    for (int j = 0; j < 4; ++j) {
      float R  = __fmaf_rn(cr[j], 1.402f, yv[j]);
      float G  = __fmaf_rn(cr[j], -0.714136f, __fmaf_rn(cb[j], -0.344136f, yv[j]));
      float Bv = __fmaf_rn(cb[j], 1.772f, yv[j]);
      R  = fminf(fmaxf(R,  0.0f), 255.0f);
      G  = fminf(fmaxf(G,  0.0f), 255.0f);
      Bv = fminf(fmaxf(Bv, 0.0f), 255.0f);
      rr[j] = __fdiv_rn(R,  255.0f);
      gg[j] = __fdiv_rn(G,  255.0f);
      bb[j] = __fdiv_rn(Bv, 255.0f);
    }
    size_t o = (size_t)(row0 + py) * WW + (col0 + col);
    *(float4*)(oR + o) = make_float4(rr[0], rr[1], rr[2], rr[3]);
    *(float4*)(oG + o) = make_float4(gg[0], gg[1], gg[2], gg[3]);
    *(float4*)(oB + o) = make_float4(bb[0], bb[1], bb[2], bb[3]);
  }

  // ---- phase 4: source_image pass-through (flat contiguous slab per WG) ----
  {
    const float4* s4 = (const float4*)src;
    float4*       d4 = (float4*)(out + NELEM);
    size_t base4 = (size_t)blk * 768;
    #pragma unroll
    for (int i = 0; i < 6; ++i) {
      size_t f = base4 + i * 128 + tid;
      d4[f] = s4[f];
    }
  }
}

extern "C" void kernel_launch(void* const* d_in, const int* in_sizes, int n_in,
                              void* d_out, int out_size, void* d_ws, size_t ws_size,
                              hipStream_t stream) {
  (void)in_sizes; (void)n_in; (void)d_ws; (void)ws_size; (void)out_size;
  const float* x   = (const float*)d_in[0];
  const float* src = (const float*)d_in[1];
  float* out = (float*)d_out;

  diffjpeg_kernel<<<dim3(BATCH * 256), dim3(128), 0, stream>>>(x, src, out);
}

// Round 8
// 52.804 us; speedup vs baseline: 1.1214x; 1.1214x over previous
//
#include <hip/hip_runtime.h>
#include <math.h>

#define BATCH 16
#define HH 512
#define WW 512
#define PLANE ((size_t)HH * WW)
#define NELEM ((size_t)BATCH * 3 * PLANE)

// Quant divisor tables, reference's .T applied: QT[u][v] (small ints, exact f32)
__constant__ float QYT[8][8] = {
  {16,12,14,14,18,24,49,72},
  {11,12,13,17,22,35,64,92},
  {10,14,16,22,37,55,78,95},
  {16,19,24,29,56,64,87,98},
  {24,26,40,51,68,81,103,112},
  {40,58,57,87,109,104,121,100},
  {51,60,69,80,103,113,120,103},
  {61,55,56,62,77,92,101,99},
};
__constant__ float QCT[8][8] = {
  {17,18,24,47,99,99,99,99},
  {18,21,26,66,99,99,99,99},
  {24,26,56,99,99,99,99,99},
  {47,66,99,99,99,99,99,99},
  {99,99,99,99,99,99,99,99},
  {99,99,99,99,99,99,99,99},
  {99,99,99,99,99,99,99,99},
  {99,99,99,99,99,99,99,99},
};

// 32x64-pixel tile per 128-thread WG. Grid = 16 * 128 = 2048 WGs.
// Blocked LDS: Blk[bk][68]; bk 0..31 = Y (4x8), 32..39 = Cb, 40..47 = Cr.
extern "C" __global__ __launch_bounds__(128)
void diffjpeg_kernel(const float* __restrict__ x, const float* __restrict__ src,
                     float* __restrict__ out) {
  __shared__ float Blk[48][68];
  __shared__ float Cs[64];   // Cs[a*8+b] = f32 _COS[a][b] (numpy bit-match)

  const int blk = blockIdx.x;
  const int b   = blk >> 7;          // image 0..15
  const int t   = blk & 127;         // tile (16 rows x 8 cols of 32x64 tiles)
  const int trow = t >> 3, tcol = t & 7;
  const int row0 = trow * 32, col0 = tcol * 64;
  const int tid = threadIdx.x;

  // ---- phase 0: numpy-bitwise cos table ----
  if (tid < 64) {
    int a = tid >> 3, bb = tid & 7;
    float t2 = (float)((2 * a + 1) * bb);
    float t3 = __fmul_rn(t2, 3.14159265358979323846f);
    float t4 = __fmul_rn(t3, 0.0625f);
    Cs[tid] = (float)cos((double)t4);
  }

  const float* Rp = x + (size_t)(b * 3 + 0) * PLANE;
  const float* Gp = x + (size_t)(b * 3 + 1) * PLANE;
  const float* Bp = x + (size_t)(b * 3 + 2) * PLANE;

  // ---- phase 1: x*255 -> sgemm-FMA YCC (+128 chroma) -> 2x2 mean -> -128 ----
  #pragma unroll
  for (int i = 0; i < 4; ++i) {
    int q  = tid + i * 128;          // quad 0..511 (16 rows x 32 cols of 2x2 px)
    int qy = q >> 5, qx = q & 31;
    size_t base = (size_t)(row0 + 2 * qy) * WW + (col0 + 2 * qx);
    float2 r0 = *(const float2*)(Rp + base);
    float2 r1 = *(const float2*)(Rp + base + WW);
    float2 g0 = *(const float2*)(Gp + base);
    float2 g1 = *(const float2*)(Gp + base + WW);
    float2 b0 = *(const float2*)(Bp + base);
    float2 b1 = *(const float2*)(Bp + base + WW);

    float rf[4] = {r0.x, r0.y, r1.x, r1.y};
    float gf[4] = {g0.x, g0.y, g1.x, g1.y};
    float bf[4] = {b0.x, b0.y, b1.x, b1.y};
    float Ym[4], CB[4], CR[4];
    #pragma unroll
    for (int j = 0; j < 4; ++j) {
      float R  = __fmul_rn(rf[j], 255.0f);
      float G  = __fmul_rn(gf[j], 255.0f);
      float Bv = __fmul_rn(bf[j], 255.0f);
      float Yv = __fmaf_rn(Bv, 0.114f, __fmaf_rn(G, 0.587f, __fmul_rn(R, 0.299f)));
      Ym[j] = __fsub_rn(Yv, 128.0f);               // DCT input shift (moved)
      CB[j] = __fadd_rn(
          __fmaf_rn(Bv, 0.5f, __fmaf_rn(G, -0.331264f, __fmul_rn(R, -0.168736f))),
          128.0f);
      CR[j] = __fadd_rn(
          __fmaf_rn(Bv, -0.081312f, __fmaf_rn(G, -0.418688f, __fmul_rn(R, 0.5f))),
          128.0f);
    }

    int ybk = (qy >> 2) * 8 + (qx >> 2);
    int xin = (qy & 3) * 2, yin = (qx & 3) * 2;
    float* Pb = Blk[ybk];
    *(float2*)&Pb[xin * 8 + yin]       = make_float2(Ym[0], Ym[1]);
    *(float2*)&Pb[(xin + 1) * 8 + yin] = make_float2(Ym[2], Ym[3]);

    float sb = __fadd_rn(__fadd_rn(__fadd_rn(CB[0], CB[1]), CB[2]), CB[3]);
    float sr = __fadd_rn(__fadd_rn(__fadd_rn(CR[0], CR[1]), CR[2]), CR[3]);
    int cbk = 32 + (qy >> 3) * 4 + (qx >> 3);
    int coff = (qy & 7) * 8 + (qx & 7);
    // /4.0 == *0.25 exactly (power-of-two, bit-identical)
    Blk[cbk][coff]     = __fsub_rn(__fmul_rn(sb, 0.25f), 128.0f);
    Blk[cbk + 8][coff] = __fsub_rn(__fmul_rn(sr, 0.25f), 128.0f);
  }
  __syncthreads();

  // ---- phase 2: lane owns coefficient (u,v); wave owns 24 blocks ----
  const int w    = tid >> 6;
  const int lane = tid & 63;
  const int u = lane >> 3, v = lane & 7;
  const float au = (u == 0) ? 0.70710678118654746f : 1.0f;
  const float av = (v == 0) ? 0.70710678118654746f : 1.0f;
  const float ao  = __fmul_rn(au, av);        // ALPHA_OUTER[u][v]
  const float sc  = __fmul_rn(ao, 0.25f);     // SCALE[u][v]
  const float qdY = __fmul_rn(QYT[u][v], 0.4f);
  const float qdC = __fmul_rn(QCT[u][v], 0.4f);
  const int  bk0  = w * 24;

  float cuA[8], cvA[8];   // DCT factor rows: cuA[x]=Cs[x*8+u], cvA[y]=Cs[y*8+v]
  #pragma unroll
  for (int k = 0; k < 8; ++k) { cuA[k] = Cs[k * 8 + u]; cvA[k] = Cs[k * 8 + v]; }

  // ---- 2a: chunked DCT: per 16-k chunk build W[16], run 24 acc chains ----
  {
    float acc[24];
    #pragma unroll
    for (int j = 0; j < 24; ++j) acc[j] = 0.f;
    #pragma unroll
    for (int ch = 0; ch < 4; ++ch) {
      float W[16];
      #pragma unroll
      for (int xy = 0; xy < 16; ++xy) {
        int k = ch * 16 + xy;
        W[xy] = __fmul_rn(cuA[k >> 3], cvA[k & 7]);   // f32 DCT_T entry
      }
      #pragma unroll
      for (int j = 0; j < 24; ++j) {
        const float* A = Blk[bk0 + j] + ch * 16;      // wave-uniform broadcast
        float4 a0 = *(const float4*)(A);
        float4 a1 = *(const float4*)(A + 4);
        float4 a2 = *(const float4*)(A + 8);
        float4 a3 = *(const float4*)(A + 12);
        float s = acc[j];
        s = __fmaf_rn(a0.x, W[ 0], s); s = __fmaf_rn(a0.y, W[ 1], s);
        s = __fmaf_rn(a0.z, W[ 2], s); s = __fmaf_rn(a0.w, W[ 3], s);
        s = __fmaf_rn(a1.x, W[ 4], s); s = __fmaf_rn(a1.y, W[ 5], s);
        s = __fmaf_rn(a1.z, W[ 6], s); s = __fmaf_rn(a1.w, W[ 7], s);
        s = __fmaf_rn(a2.x, W[ 8], s); s = __fmaf_rn(a2.y, W[ 9], s);
        s = __fmaf_rn(a2.z, W[10], s); s = __fmaf_rn(a2.w, W[11], s);
        s = __fmaf_rn(a3.x, W[12], s); s = __fmaf_rn(a3.y, W[13], s);
        s = __fmaf_rn(a3.z, W[14], s); s = __fmaf_rn(a3.w, W[15], s);
        acc[j] = s;
      }
    }
    // quant + diff_round + dequant(*AO), write back in place
    #pragma unroll
    for (int j = 0; j < 24; ++j) {
      int bk = bk0 + j;
      float qd = (bk < 32) ? qdY : qdC;
      float Sp = __fmul_rn(sc, acc[j]);
      float qv = __fdiv_rn(Sp, qd);
      float r  = rintf(qv);
      float dd = __fsub_rn(qv, r);
      float e  = __fadd_rn(r, __fmul_rn(__fmul_rn(dd, dd), dd));
      Blk[bk][lane] = __fmul_rn(__fmul_rn(e, qd), ao);   // lane = u*8+v
    }
  }

  // ---- 2b: chunked IDCT (lane owns spatial (u,v)), *0.25, +128 ----
  {
    float cuB[8], cvB[8];  // cuB[x]=Cs[u*8+x], cvB[y]=Cs[v*8+y]
    #pragma unroll
    for (int k = 0; k < 8; ++k) { cuB[k] = Cs[u * 8 + k]; cvB[k] = Cs[v * 8 + k]; }
    float acc[24];
    #pragma unroll
    for (int j = 0; j < 24; ++j) acc[j] = 0.f;
    #pragma unroll
    for (int ch = 0; ch < 4; ++ch) {
      float W[16];
      #pragma unroll
      for (int xy = 0; xy < 16; ++xy) {
        int k = ch * 16 + xy;
        W[xy] = __fmul_rn(cuB[k >> 3], cvB[k & 7]);   // f32 IDCT_T entry
      }
      #pragma unroll
      for (int j = 0; j < 24; ++j) {
        const float* A = Blk[bk0 + j] + ch * 16;
        float4 a0 = *(const float4*)(A);
        float4 a1 = *(const float4*)(A + 4);
        float4 a2 = *(const float4*)(A + 8);
        float4 a3 = *(const float4*)(A + 12);
        float s = acc[j];
        s = __fmaf_rn(a0.x, W[ 0], s); s = __fmaf_rn(a0.y, W[ 1], s);
        s = __fmaf_rn(a0.z, W[ 2], s); s = __fmaf_rn(a0.w, W[ 3], s);
        s = __fmaf_rn(a1.x, W[ 4], s); s = __fmaf_rn(a1.y, W[ 5], s);
        s = __fmaf_rn(a1.z, W[ 6], s); s = __fmaf_rn(a1.w, W[ 7], s);
        s = __fmaf_rn(a2.x, W[ 8], s); s = __fmaf_rn(a2.y, W[ 9], s);
        s = __fmaf_rn(a2.z, W[10], s); s = __fmaf_rn(a2.w, W[11], s);
        s = __fmaf_rn(a3.x, W[12], s); s = __fmaf_rn(a3.y, W[13], s);
        s = __fmaf_rn(a3.z, W[14], s); s = __fmaf_rn(a3.w, W[15], s);
        acc[j] = s;
      }
    }
    #pragma unroll
    for (int j = 0; j < 24; ++j)
      Blk[bk0 + j][lane] = __fadd_rn(__fmul_rn(0.25f, acc[j]), 128.0f);
  }

  // ---- phase 4 (early): source_image pass-through; overlaps barrier wait ----
  {
    const float4* s4 = (const float4*)src;
    float4*       d4 = (float4*)(out + NELEM);
    size_t base4 = (size_t)blk * 1536;
    #pragma unroll
    for (int i = 0; i < 12; ++i) {
      size_t f = base4 + i * 128 + tid;
      d4[f] = s4[f];
    }
  }
  __syncthreads();

  // ---- phase 3: upsample, -128, sgemm-FMA YCC->RGB, clip, /255, store ----
  float* oR = out + (size_t)(b * 3 + 0) * PLANE;
  float* oG = out + (size_t)(b * 3 + 1) * PLANE;
  float* oB = out + (size_t)(b * 3 + 2) * PLANE;
  #pragma unroll
  for (int i = 0; i < 4; ++i) {
    int g = tid + i * 128;           // 32 rows x 16 groups of 4 px
    int py = g >> 4, pxg = g & 15;
    int col = pxg * 4;
    int ybk = (py >> 3) * 8 + (col >> 3);
    int yoff = (py & 7) * 8 + (col & 7);
    float4 yv4 = *(const float4*)&Blk[ybk][yoff];
    float yv[4] = {yv4.x, yv4.y, yv4.z, yv4.w};

    int cy = py >> 1, cx = 2 * pxg;
    int cbk = 32 + (cy >> 3) * 4 + (cx >> 3);
    int coff = (cy & 7) * 8 + (cx & 7);
    float2 cbv = *(const float2*)&Blk[cbk][coff];
    float2 crv = *(const float2*)&Blk[cbk + 8][coff];
    float cb0 = __fadd_rn(cbv.x, -128.0f);
    float cb1 = __fadd_rn(cbv.y, -128.0f);
    float cr0 = __fadd_rn(crv.x, -128.0f);
    float cr1 = __fadd_rn(crv.y, -128.0f);
    float cb[4] = {cb0, cb0, cb1, cb1};
    float cr[4] = {cr0, cr0, cr1, cr1};

    float rr[4], gg[4], bb[4];
    #pragma unroll
    for (int j = 0; j < 4; ++j) {
      float R  = __fmaf_rn(cr[j], 1.402f, yv[j]);
      float G  = __fmaf_rn(cr[j], -0.714136f, __fmaf_rn(cb[j], -0.344136f, yv[j]));
      float Bv = __fmaf_rn(cb[j], 1.772f, yv[j]);
      R  = fminf(fmaxf(R,  0.0f), 255.0f);
      G  = fminf(fmaxf(G,  0.0f), 255.0f);
      Bv = fminf(fmaxf(Bv, 0.0f), 255.0f);
      rr[j] = __fdiv_rn(R,  255.0f);
      gg[j] = __fdiv_rn(G,  255.0f);
      bb[j] = __fdiv_rn(Bv, 255.0f);
    }
    size_t o = (size_t)(row0 + py) * WW + (col0 + col);
    *(float4*)(oR + o) = make_float4(rr[0], rr[1], rr[2], rr[3]);
    *(float4*)(oG + o) = make_float4(gg[0], gg[1], gg[2], gg[3]);
    *(float4*)(oB + o) = make_float4(bb[0], bb[1], bb[2], bb[3]);
  }
}

extern "C" void kernel_launch(void* const* d_in, const int* in_sizes, int n_in,
                              void* d_out, int out_size, void* d_ws, size_t ws_size,
                              hipStream_t stream) {
  (void)in_sizes; (void)n_in; (void)d_ws; (void)ws_size; (void)out_size;
  const float* x   = (const float*)d_in[0];
  const float* src = (const float*)d_in[1];
  float* out = (float*)d_out;

  diffjpeg_kernel<<<dim3(BATCH * 128), dim3(128), 0, stream>>>(x, src, out);
}

// Round 9
// 46.948 us; speedup vs baseline: 1.2612x; 1.1247x over previous
//
#include <hip/hip_runtime.h>
#include <math.h>

#define BATCH 16
#define HH 512
#define WW 512
#define PLANE ((size_t)HH * WW)
#define NELEM ((size_t)BATCH * 3 * PLANE)

// Quant divisor tables, reference's .T applied: QT[u][v] (small ints, exact f32)
__constant__ float QYT[8][8] = {
  {16,12,14,14,18,24,49,72},
  {11,12,13,17,22,35,64,92},
  {10,14,16,22,37,55,78,95},
  {16,19,24,29,56,64,87,98},
  {24,26,40,51,68,81,103,112},
  {40,58,57,87,109,104,121,100},
  {51,60,69,80,103,113,120,103},
  {61,55,56,62,77,92,101,99},
};
__constant__ float QCT[8][8] = {
  {17,18,24,47,99,99,99,99},
  {18,21,26,66,99,99,99,99},
  {24,26,56,99,99,99,99,99},
  {47,66,99,99,99,99,99,99},
  {99,99,99,99,99,99,99,99},
  {99,99,99,99,99,99,99,99},
  {99,99,99,99,99,99,99,99},
  {99,99,99,99,99,99,99,99},
};

// 32x64-pixel tile per 256-thread WG (4 waves). Grid = 2048 WGs = 8 WG/CU
// -> 32 waves/CU resident (100% of cap). LDS 13.3 KB, VGPR capped <=64.
// Blocked LDS: Blk[bk][68]; bk 0..31 = Y (4x8), 32..39 = Cb, 40..47 = Cr.
extern "C" __global__ __launch_bounds__(256, 8)
void diffjpeg_kernel(const float* __restrict__ x, const float* __restrict__ src,
                     float* __restrict__ out) {
  __shared__ float Blk[48][68];
  __shared__ float Cs[64];   // Cs[a*8+b] = f32 _COS[a][b] (numpy bit-match)

  const int blk = blockIdx.x;
  const int b   = blk >> 7;          // image 0..15
  const int t   = blk & 127;         // tile (16 rows x 8 cols of 32x64 tiles)
  const int trow = t >> 3, tcol = t & 7;
  const int row0 = trow * 32, col0 = tcol * 64;
  const int tid = threadIdx.x;

  // ---- phase 0: numpy-bitwise cos table ----
  if (tid < 64) {
    int a = tid >> 3, bb = tid & 7;
    float t2 = (float)((2 * a + 1) * bb);
    float t3 = __fmul_rn(t2, 3.14159265358979323846f);
    float t4 = __fmul_rn(t3, 0.0625f);
    Cs[tid] = (float)cos((double)t4);
  }

  const float* Rp = x + (size_t)(b * 3 + 0) * PLANE;
  const float* Gp = x + (size_t)(b * 3 + 1) * PLANE;
  const float* Bp = x + (size_t)(b * 3 + 2) * PLANE;

  // ---- phase 1: thread owns 2 rows x 4 cols; float4 loads; YCC; 2x2 mean ----
  {
    int uy = tid >> 4, ux = tid & 15;       // 16 row-pairs x 16 col-quads
    size_t base = (size_t)(row0 + 2 * uy) * WW + (col0 + 4 * ux);
    float4 r0 = *(const float4*)(Rp + base);
    float4 r1 = *(const float4*)(Rp + base + WW);
    float4 g0 = *(const float4*)(Gp + base);
    float4 g1 = *(const float4*)(Gp + base + WW);
    float4 b0 = *(const float4*)(Bp + base);
    float4 b1 = *(const float4*)(Bp + base + WW);

    // order per 2x2 quad: top-left, top-right, bot-left, bot-right (as before)
    float rf[8] = {r0.x, r0.y, r1.x, r1.y,  r0.z, r0.w, r1.z, r1.w};
    float gf[8] = {g0.x, g0.y, g1.x, g1.y,  g0.z, g0.w, g1.z, g1.w};
    float bf[8] = {b0.x, b0.y, b1.x, b1.y,  b0.z, b0.w, b1.z, b1.w};
    float Ym[8], CB[8], CR[8];
    #pragma unroll
    for (int j = 0; j < 8; ++j) {
      float R  = __fmul_rn(rf[j], 255.0f);
      float G  = __fmul_rn(gf[j], 255.0f);
      float Bv = __fmul_rn(bf[j], 255.0f);
      float Yv = __fmaf_rn(Bv, 0.114f, __fmaf_rn(G, 0.587f, __fmul_rn(R, 0.299f)));
      Ym[j] = __fsub_rn(Yv, 128.0f);               // DCT input shift (moved)
      CB[j] = __fadd_rn(
          __fmaf_rn(Bv, 0.5f, __fmaf_rn(G, -0.331264f, __fmul_rn(R, -0.168736f))),
          128.0f);
      CR[j] = __fadd_rn(
          __fmaf_rn(Bv, -0.081312f, __fmaf_rn(G, -0.418688f, __fmul_rn(R, 0.5f))),
          128.0f);
    }

    int ybk = (uy >> 2) * 8 + (ux >> 1);
    int xin = (uy & 3) * 2, yin = (ux & 1) * 4;
    // rows: [q0TL,q0TR,q1TL,q1TR] top, [q0BL,q0BR,q1BL,q1BR] bottom
    *(float4*)&Blk[ybk][xin * 8 + yin] =
        make_float4(Ym[0], Ym[1], Ym[4], Ym[5]);
    *(float4*)&Blk[ybk][(xin + 1) * 8 + yin] =
        make_float4(Ym[2], Ym[3], Ym[6], Ym[7]);

    // per-quad mean: ((TL+TR)+BL)+BR, *0.25 (==/4, exact), -128
    float sb0 = __fadd_rn(__fadd_rn(__fadd_rn(CB[0], CB[1]), CB[2]), CB[3]);
    float sb1 = __fadd_rn(__fadd_rn(__fadd_rn(CB[4], CB[5]), CB[6]), CB[7]);
    float sr0 = __fadd_rn(__fadd_rn(__fadd_rn(CR[0], CR[1]), CR[2]), CR[3]);
    float sr1 = __fadd_rn(__fadd_rn(__fadd_rn(CR[4], CR[5]), CR[6]), CR[7]);
    int cbk = 32 + (uy >> 3) * 4 + (ux >> 2);
    int coff = (uy & 7) * 8 + ((2 * ux) & 7);
    *(float2*)&Blk[cbk][coff] = make_float2(
        __fsub_rn(__fmul_rn(sb0, 0.25f), 128.0f),
        __fsub_rn(__fmul_rn(sb1, 0.25f), 128.0f));
    *(float2*)&Blk[cbk + 8][coff] = make_float2(
        __fsub_rn(__fmul_rn(sr0, 0.25f), 128.0f),
        __fsub_rn(__fmul_rn(sr1, 0.25f), 128.0f));
  }
  __syncthreads();

  // ---- phase 2: lane owns coefficient (u,v); wave owns 12 blocks ----
  const int w    = tid >> 6;
  const int lane = tid & 63;
  const int u = lane >> 3, v = lane & 7;
  const float au = (u == 0) ? 0.70710678118654746f : 1.0f;
  const float av = (v == 0) ? 0.70710678118654746f : 1.0f;
  const float ao  = __fmul_rn(au, av);        // ALPHA_OUTER[u][v]
  const float sc  = __fmul_rn(ao, 0.25f);     // SCALE[u][v]
  const float qdY = __fmul_rn(QYT[u][v], 0.4f);
  const float qdC = __fmul_rn(QCT[u][v], 0.4f);
  const int  bk0  = w * 12;

  // ---- 2a: chunked DCT: per 16-k chunk build W[16], run 12 acc chains ----
  {
    float cuA[8], cvA[8];   // cuA[x]=Cs[x*8+u], cvA[y]=Cs[y*8+v]
    #pragma unroll
    for (int k = 0; k < 8; ++k) { cuA[k] = Cs[k * 8 + u]; cvA[k] = Cs[k * 8 + v]; }
    float acc[12];
    #pragma unroll
    for (int j = 0; j < 12; ++j) acc[j] = 0.f;
    #pragma unroll
    for (int ch = 0; ch < 4; ++ch) {
      float W[16];
      #pragma unroll
      for (int xy = 0; xy < 16; ++xy) {
        int k = ch * 16 + xy;
        W[xy] = __fmul_rn(cuA[k >> 3], cvA[k & 7]);   // f32 DCT_T entry
      }
      #pragma unroll
      for (int j = 0; j < 12; ++j) {
        const float* A = Blk[bk0 + j] + ch * 16;      // wave-uniform broadcast
        float4 a0 = *(const float4*)(A);
        float4 a1 = *(const float4*)(A + 4);
        float4 a2 = *(const float4*)(A + 8);
        float4 a3 = *(const float4*)(A + 12);
        float s = acc[j];
        s = __fmaf_rn(a0.x, W[ 0], s); s = __fmaf_rn(a0.y, W[ 1], s);
        s = __fmaf_rn(a0.z, W[ 2], s); s = __fmaf_rn(a0.w, W[ 3], s);
        s = __fmaf_rn(a1.x, W[ 4], s); s = __fmaf_rn(a1.y, W[ 5], s);
        s = __fmaf_rn(a1.z, W[ 6], s); s = __fmaf_rn(a1.w, W[ 7], s);
        s = __fmaf_rn(a2.x, W[ 8], s); s = __fmaf_rn(a2.y, W[ 9], s);
        s = __fmaf_rn(a2.z, W[10], s); s = __fmaf_rn(a2.w, W[11], s);
        s = __fmaf_rn(a3.x, W[12], s); s = __fmaf_rn(a3.y, W[13], s);
        s = __fmaf_rn(a3.z, W[14], s); s = __fmaf_rn(a3.w, W[15], s);
        acc[j] = s;
      }
    }
    // quant + diff_round + dequant(*AO), write back in place (own blocks)
    #pragma unroll
    for (int j = 0; j < 12; ++j) {
      int bk = bk0 + j;
      float qd = (bk < 32) ? qdY : qdC;
      float Sp = __fmul_rn(sc, acc[j]);
      float qv = __fdiv_rn(Sp, qd);
      float r  = rintf(qv);
      float dd = __fsub_rn(qv, r);
      float e  = __fadd_rn(r, __fmul_rn(__fmul_rn(dd, dd), dd));
      Blk[bk][lane] = __fmul_rn(__fmul_rn(e, qd), ao);   // lane = u*8+v
    }
  }

  // ---- 2b: chunked IDCT (lane owns spatial (u,v)), *0.25, +128 ----
  {
    float cuB[8], cvB[8];  // cuB[x]=Cs[u*8+x], cvB[y]=Cs[v*8+y]
    #pragma unroll
    for (int k = 0; k < 8; ++k) { cuB[k] = Cs[u * 8 + k]; cvB[k] = Cs[v * 8 + k]; }
    float acc[12];
    #pragma unroll
    for (int j = 0; j < 12; ++j) acc[j] = 0.f;
    #pragma unroll
    for (int ch = 0; ch < 4; ++ch) {
      float W[16];
      #pragma unroll
      for (int xy = 0; xy < 16; ++xy) {
        int k = ch * 16 + xy;
        W[xy] = __fmul_rn(cuB[k >> 3], cvB[k & 7]);   // f32 IDCT_T entry
      }
      #pragma unroll
      for (int j = 0; j < 12; ++j) {
        const float* A = Blk[bk0 + j] + ch * 16;
        float4 a0 = *(const float4*)(A);
        float4 a1 = *(const float4*)(A + 4);
        float4 a2 = *(const float4*)(A + 8);
        float4 a3 = *(const float4*)(A + 12);
        float s = acc[j];
        s = __fmaf_rn(a0.x, W[ 0], s); s = __fmaf_rn(a0.y, W[ 1], s);
        s = __fmaf_rn(a0.z, W[ 2], s); s = __fmaf_rn(a0.w, W[ 3], s);
        s = __fmaf_rn(a1.x, W[ 4], s); s = __fmaf_rn(a1.y, W[ 5], s);
        s = __fmaf_rn(a1.z, W[ 6], s); s = __fmaf_rn(a1.w, W[ 7], s);
        s = __fmaf_rn(a2.x, W[ 8], s); s = __fmaf_rn(a2.y, W[ 9], s);
        s = __fmaf_rn(a2.z, W[10], s); s = __fmaf_rn(a2.w, W[11], s);
        s = __fmaf_rn(a3.x, W[12], s); s = __fmaf_rn(a3.y, W[13], s);
        s = __fmaf_rn(a3.z, W[14], s); s = __fmaf_rn(a3.w, W[15], s);
        acc[j] = s;
      }
    }
    #pragma unroll
    for (int j = 0; j < 12; ++j)
      Blk[bk0 + j][lane] = __fadd_rn(__fmul_rn(0.25f, acc[j]), 128.0f);
  }

  // ---- phase 4 (early): source_image pass-through; overlaps barrier wait ----
  {
    const float4* s4 = (const float4*)src;
    float4*       d4 = (float4*)(out + NELEM);
    size_t base4 = (size_t)blk * 1536;
    #pragma unroll
    for (int i = 0; i < 6; ++i) {
      size_t f = base4 + i * 256 + tid;
      d4[f] = s4[f];
    }
  }
  __syncthreads();

  // ---- phase 3: upsample, -128, sgemm-FMA YCC->RGB, clip, /255, store ----
  float* oR = out + (size_t)(b * 3 + 0) * PLANE;
  float* oG = out + (size_t)(b * 3 + 1) * PLANE;
  float* oB = out + (size_t)(b * 3 + 2) * PLANE;
  #pragma unroll
  for (int i = 0; i < 2; ++i) {
    int g = tid + i * 256;           // 32 rows x 16 groups of 4 px
    int py = g >> 4, pxg = g & 15;
    int col = pxg * 4;
    int ybk = (py >> 3) * 8 + (col >> 3);
    int yoff = (py & 7) * 8 + (col & 7);
    float4 yv4 = *(const float4*)&Blk[ybk][yoff];
    float yv[4] = {yv4.x, yv4.y, yv4.z, yv4.w};

    int cy = py >> 1, cx = 2 * pxg;
    int cbk = 32 + (cy >> 3) * 4 + (cx >> 3);
    int coff = (cy & 7) * 8 + (cx & 7);
    float2 cbv = *(const float2*)&Blk[cbk][coff];
    float2 crv = *(const float2*)&Blk[cbk + 8][coff];
    float cb0 = __fadd_rn(cbv.x, -128.0f);
    float cb1 = __fadd_rn(cbv.y, -128.0f);
    float cr0 = __fadd_rn(crv.x, -128.0f);
    float cr1 = __fadd_rn(crv.y, -128.0f);
    float cb[4] = {cb0, cb0, cb1, cb1};
    float cr[4] = {cr0, cr0, cr1, cr1};

    float rr[4], gg[4], bb[4];
    #pragma unroll
    for (int j = 0; j < 4; ++j) {
      float R  = __fmaf_rn(cr[j], 1.402f, yv[j]);
      float G  = __fmaf_rn(cr[j], -0.714136f, __fmaf_rn(cb[j], -0.344136f, yv[j]));
      float Bv = __fmaf_rn(cb[j], 1.772f, yv[j]);
      R  = fminf(fmaxf(R,  0.0f), 255.0f);
      G  = fminf(fmaxf(G,  0.0f), 255.0f);
      Bv = fminf(fmaxf(Bv, 0.0f), 255.0f);
      rr[j] = __fdiv_rn(R,  255.0f);
      gg[j] = __fdiv_rn(G,  255.0f);
      bb[j] = __fdiv_rn(Bv, 255.0f);
    }
    size_t o = (size_t)(row0 + py) * WW + (col0 + col);
    *(float4*)(oR + o) = make_float4(rr[0], rr[1], rr[2], rr[3]);
    *(float4*)(oG + o) = make_float4(gg[0], gg[1], gg[2], gg[3]);
    *(float4*)(oB + o) = make_float4(bb[0], bb[1], bb[2], bb[3]);
  }
}

extern "C" void kernel_launch(void* const* d_in, const int* in_sizes, int n_in,
                              void* d_out, int out_size, void* d_ws, size_t ws_size,
                              hipStream_t stream) {
  (void)in_sizes; (void)n_in; (void)d_ws; (void)ws_size; (void)out_size;
  const float* x   = (const float*)d_in[0];
  const float* src = (const float*)d_in[1];
  float* out = (float*)d_out;

  diffjpeg_kernel<<<dim3(BATCH * 128), dim3(256), 0, stream>>>(x, src, out);
}

// Round 10
// 39.235 us; speedup vs baseline: 1.5091x; 1.1966x over previous
//
#include <hip/hip_runtime.h>
#include <math.h>

#define BATCH 16
#define HH 512
#define WW 512
#define PLANE ((size_t)HH * WW)
#define NELEM ((size_t)BATCH * 3 * PLANE)

// Quant divisor tables, reference's .T applied: QT[u][v] (small ints, exact f32)
__constant__ float QYT[8][8] = {
  {16,12,14,14,18,24,49,72},
  {11,12,13,17,22,35,64,92},
  {10,14,16,22,37,55,78,95},
  {16,19,24,29,56,64,87,98},
  {24,26,40,51,68,81,103,112},
  {40,58,57,87,109,104,121,100},
  {51,60,69,80,103,113,120,103},
  {61,55,56,62,77,92,101,99},
};
__constant__ float QCT[8][8] = {
  {17,18,24,47,99,99,99,99},
  {18,21,26,66,99,99,99,99},
  {24,26,56,99,99,99,99,99},
  {47,66,99,99,99,99,99,99},
  {99,99,99,99,99,99,99,99},
  {99,99,99,99,99,99,99,99},
  {99,99,99,99,99,99,99,99},
  {99,99,99,99,99,99,99,99},
};

// 32x64-pixel tile per 256-thread WG (4 waves). Grid = 2048 WGs = 8 WG/CU
// -> 32 waves/CU. Blocked LDS: Blk[bk][68]; 0..31 Y, 32..39 Cb, 40..47 Cr.
extern "C" __global__ __launch_bounds__(256, 8)
void diffjpeg_kernel(const float* __restrict__ x, const float* __restrict__ src,
                     float* __restrict__ out) {
  __shared__ float Blk[48][68];
  __shared__ float Cs[64];   // Cs[a*8+b] = f32 _COS[a][b] (numpy bit-match)

  const int blk = blockIdx.x;
  const int b   = blk >> 7;          // image 0..15
  const int t   = blk & 127;         // tile (16 rows x 8 cols of 32x64 tiles)
  const int trow = t >> 3, tcol = t & 7;
  const int row0 = trow * 32, col0 = tcol * 64;
  const int tid = threadIdx.x;

  // ---- phase 0: numpy-bitwise cos table ----
  if (tid < 64) {
    int a = tid >> 3, bb = tid & 7;
    float t2 = (float)((2 * a + 1) * bb);
    float t3 = __fmul_rn(t2, 3.14159265358979323846f);
    float t4 = __fmul_rn(t3, 0.0625f);
    Cs[tid] = (float)cos((double)t4);
  }

  const float* Rp = x + (size_t)(b * 3 + 0) * PLANE;
  const float* Gp = x + (size_t)(b * 3 + 1) * PLANE;
  const float* Bp = x + (size_t)(b * 3 + 2) * PLANE;

  // ---- phase 1: thread owns 2 rows x 4 cols; float4 loads; YCC; 2x2 mean ----
  {
    int uy = tid >> 4, ux = tid & 15;       // 16 row-pairs x 16 col-quads
    size_t base = (size_t)(row0 + 2 * uy) * WW + (col0 + 4 * ux);
    float4 r0 = *(const float4*)(Rp + base);
    float4 r1 = *(const float4*)(Rp + base + WW);
    float4 g0 = *(const float4*)(Gp + base);
    float4 g1 = *(const float4*)(Gp + base + WW);
    float4 b0 = *(const float4*)(Bp + base);
    float4 b1 = *(const float4*)(Bp + base + WW);

    float rf[8] = {r0.x, r0.y, r1.x, r1.y,  r0.z, r0.w, r1.z, r1.w};
    float gf[8] = {g0.x, g0.y, g1.x, g1.y,  g0.z, g0.w, g1.z, g1.w};
    float bf[8] = {b0.x, b0.y, b1.x, b1.y,  b0.z, b0.w, b1.z, b1.w};
    float Ym[8], CB[8], CR[8];
    #pragma unroll
    for (int j = 0; j < 8; ++j) {
      float R  = __fmul_rn(rf[j], 255.0f);
      float G  = __fmul_rn(gf[j], 255.0f);
      float Bv = __fmul_rn(bf[j], 255.0f);
      float Yv = __fmaf_rn(Bv, 0.114f, __fmaf_rn(G, 0.587f, __fmul_rn(R, 0.299f)));
      Ym[j] = __fsub_rn(Yv, 128.0f);               // DCT input shift (moved)
      CB[j] = __fadd_rn(
          __fmaf_rn(Bv, 0.5f, __fmaf_rn(G, -0.331264f, __fmul_rn(R, -0.168736f))),
          128.0f);
      CR[j] = __fadd_rn(
          __fmaf_rn(Bv, -0.081312f, __fmaf_rn(G, -0.418688f, __fmul_rn(R, 0.5f))),
          128.0f);
    }

    int ybk = (uy >> 2) * 8 + (ux >> 1);
    int xin = (uy & 3) * 2, yin = (ux & 1) * 4;
    *(float4*)&Blk[ybk][xin * 8 + yin] =
        make_float4(Ym[0], Ym[1], Ym[4], Ym[5]);
    *(float4*)&Blk[ybk][(xin + 1) * 8 + yin] =
        make_float4(Ym[2], Ym[3], Ym[6], Ym[7]);

    float sb0 = __fadd_rn(__fadd_rn(__fadd_rn(CB[0], CB[1]), CB[2]), CB[3]);
    float sb1 = __fadd_rn(__fadd_rn(__fadd_rn(CB[4], CB[5]), CB[6]), CB[7]);
    float sr0 = __fadd_rn(__fadd_rn(__fadd_rn(CR[0], CR[1]), CR[2]), CR[3]);
    float sr1 = __fadd_rn(__fadd_rn(__fadd_rn(CR[4], CR[5]), CR[6]), CR[7]);
    int cbk = 32 + (uy >> 3) * 4 + (ux >> 2);
    int coff = (uy & 7) * 8 + ((2 * ux) & 7);
    *(float2*)&Blk[cbk][coff] = make_float2(
        __fsub_rn(__fmul_rn(sb0, 0.25f), 128.0f),
        __fsub_rn(__fmul_rn(sb1, 0.25f), 128.0f));
    *(float2*)&Blk[cbk + 8][coff] = make_float2(
        __fsub_rn(__fmul_rn(sr0, 0.25f), 128.0f),
        __fsub_rn(__fmul_rn(sr1, 0.25f), 128.0f));
  }
  __syncthreads();

  // ---- phase 2: lane owns coefficient (u,v); wave owns 12 blocks ----
  const int w    = tid >> 6;
  const int lane = tid & 63;
  const int u = lane >> 3, v = lane & 7;
  const float au = (u == 0) ? 0.70710678118654746f : 1.0f;
  const float av = (v == 0) ? 0.70710678118654746f : 1.0f;
  const float ao  = __fmul_rn(au, av);        // ALPHA_OUTER[u][v]
  const float sc  = __fmul_rn(ao, 0.25f);     // SCALE[u][v]
  const float qdY = __fmul_rn(QYT[u][v], 0.4f);
  const float qdC = __fmul_rn(QCT[u][v], 0.4f);
  const int  bk0  = w * 12;

  // ---- 2a: non-separable DCT (bit-exact np chain) + quant + diff_round ----
  {
    float cuA[8], cvA[8];   // cuA[x]=Cs[x*8+u], cvA[y]=Cs[y*8+v]
    #pragma unroll
    for (int k = 0; k < 8; ++k) { cuA[k] = Cs[k * 8 + u]; cvA[k] = Cs[k * 8 + v]; }
    float acc[12];
    #pragma unroll
    for (int j = 0; j < 12; ++j) acc[j] = 0.f;
    #pragma unroll
    for (int ch = 0; ch < 4; ++ch) {
      float W[16];
      #pragma unroll
      for (int xy = 0; xy < 16; ++xy) {
        int k = ch * 16 + xy;
        W[xy] = __fmul_rn(cuA[k >> 3], cvA[k & 7]);   // f32 DCT_T entry
      }
      #pragma unroll
      for (int j = 0; j < 12; ++j) {
        const float* A = Blk[bk0 + j] + ch * 16;      // wave-uniform broadcast
        float4 a0 = *(const float4*)(A);
        float4 a1 = *(const float4*)(A + 4);
        float4 a2 = *(const float4*)(A + 8);
        float4 a3 = *(const float4*)(A + 12);
        float s = acc[j];
        s = __fmaf_rn(a0.x, W[ 0], s); s = __fmaf_rn(a0.y, W[ 1], s);
        s = __fmaf_rn(a0.z, W[ 2], s); s = __fmaf_rn(a0.w, W[ 3], s);
        s = __fmaf_rn(a1.x, W[ 4], s); s = __fmaf_rn(a1.y, W[ 5], s);
        s = __fmaf_rn(a1.z, W[ 6], s); s = __fmaf_rn(a1.w, W[ 7], s);
        s = __fmaf_rn(a2.x, W[ 8], s); s = __fmaf_rn(a2.y, W[ 9], s);
        s = __fmaf_rn(a2.z, W[10], s); s = __fmaf_rn(a2.w, W[11], s);
        s = __fmaf_rn(a3.x, W[12], s); s = __fmaf_rn(a3.y, W[13], s);
        s = __fmaf_rn(a3.z, W[14], s); s = __fmaf_rn(a3.w, W[15], s);
        acc[j] = s;
      }
    }
    #pragma unroll
    for (int j = 0; j < 12; ++j) {
      int bk = bk0 + j;
      float qd = (bk < 32) ? qdY : qdC;
      float Sp = __fmul_rn(sc, acc[j]);
      float qv = __fdiv_rn(Sp, qd);
      float r  = rintf(qv);
      float dd = __fsub_rn(qv, r);
      float e  = __fadd_rn(r, __fmul_rn(__fmul_rn(dd, dd), dd));
      Blk[bk][lane] = __fmul_rn(__fmul_rn(e, qd), ao);   // e at [u*8+v]
    }
  }

  // ---- 2b: SEPARABLE IDCT (post-round: numerically free to reorder) ----
  // pass A: lane(x=u, v): T[x][v] = sum_y e[x][y]*Cs[v*8+y]; store [v*8+x]
  // pass B: lane(u,v):    P[u][v] = 0.25*sum_x T[x][v]*Cs[u*8+x] + 128 -> [u*8+v]
  {
    float cuB[8], cvB[8];  // cuB[k]=Cs[u*8+k], cvB[k]=Cs[v*8+k]
    #pragma unroll
    for (int k = 0; k < 8; ++k) { cuB[k] = Cs[u * 8 + k]; cvB[k] = Cs[v * 8 + k]; }

    // pass A (2 blocks per iter; wave-lockstep: reads precede in-place writes)
    #pragma unroll
    for (int pb = 0; pb < 6; ++pb) {
      int bkA = bk0 + 2 * pb, bkB = bkA + 1;
      const float* A = Blk[bkA] + u * 8;   // own row x=u (32B contiguous)
      const float* C = Blk[bkB] + u * 8;
      float4 a0 = *(const float4*)(A);
      float4 a1 = *(const float4*)(A + 4);
      float4 c0 = *(const float4*)(C);
      float4 c1 = *(const float4*)(C + 4);
      float sA = __fmul_rn(a0.x, cvB[0]);
      float sB = __fmul_rn(c0.x, cvB[0]);
      sA = __fmaf_rn(a0.y, cvB[1], sA); sB = __fmaf_rn(c0.y, cvB[1], sB);
      sA = __fmaf_rn(a0.z, cvB[2], sA); sB = __fmaf_rn(c0.z, cvB[2], sB);
      sA = __fmaf_rn(a0.w, cvB[3], sA); sB = __fmaf_rn(c0.w, cvB[3], sB);
      sA = __fmaf_rn(a1.x, cvB[4], sA); sB = __fmaf_rn(c1.x, cvB[4], sB);
      sA = __fmaf_rn(a1.y, cvB[5], sA); sB = __fmaf_rn(c1.y, cvB[5], sB);
      sA = __fmaf_rn(a1.z, cvB[6], sA); sB = __fmaf_rn(c1.z, cvB[6], sB);
      sA = __fmaf_rn(a1.w, cvB[7], sA); sB = __fmaf_rn(c1.w, cvB[7], sB);
      Blk[bkA][v * 8 + u] = sA;            // transposed store (2-way banks)
      Blk[bkB][v * 8 + u] = sB;
    }

    // pass B
    #pragma unroll
    for (int pb = 0; pb < 6; ++pb) {
      int bkA = bk0 + 2 * pb, bkB = bkA + 1;
      const float* A = Blk[bkA] + v * 8;   // row v holds T[x][v], x contiguous
      const float* C = Blk[bkB] + v * 8;
      float4 a0 = *(const float4*)(A);
      float4 a1 = *(const float4*)(A + 4);
      float4 c0 = *(const float4*)(C);
      float4 c1 = *(const float4*)(C + 4);
      float sA = __fmul_rn(a0.x, cuB[0]);
      float sB = __fmul_rn(c0.x, cuB[0]);
      sA = __fmaf_rn(a0.y, cuB[1], sA); sB = __fmaf_rn(c0.y, cuB[1], sB);
      sA = __fmaf_rn(a0.z, cuB[2], sA); sB = __fmaf_rn(c0.z, cuB[2], sB);
      sA = __fmaf_rn(a0.w, cuB[3], sA); sB = __fmaf_rn(c0.w, cuB[3], sB);
      sA = __fmaf_rn(a1.x, cuB[4], sA); sB = __fmaf_rn(c1.x, cuB[4], sB);
      sA = __fmaf_rn(a1.y, cuB[5], sA); sB = __fmaf_rn(c1.y, cuB[5], sB);
      sA = __fmaf_rn(a1.z, cuB[6], sA); sB = __fmaf_rn(c1.z, cuB[6], sB);
      sA = __fmaf_rn(a1.w, cuB[7], sA); sB = __fmaf_rn(c1.w, cuB[7], sB);
      Blk[bkA][lane] = __fadd_rn(__fmul_rn(0.25f, sA), 128.0f);  // [u*8+v]
      Blk[bkB][lane] = __fadd_rn(__fmul_rn(0.25f, sB), 128.0f);
    }
  }

  // ---- phase 4 (early): source_image pass-through; overlaps barrier wait ----
  {
    const float4* s4 = (const float4*)src;
    float4*       d4 = (float4*)(out + NELEM);
    size_t base4 = (size_t)blk * 1536;
    #pragma unroll
    for (int i = 0; i < 6; ++i) {
      size_t f = base4 + i * 256 + tid;
      d4[f] = s4[f];
    }
  }
  __syncthreads();

  // ---- phase 3: upsample, -128, sgemm-FMA YCC->RGB, clip, /255, store ----
  float* oR = out + (size_t)(b * 3 + 0) * PLANE;
  float* oG = out + (size_t)(b * 3 + 1) * PLANE;
  float* oB = out + (size_t)(b * 3 + 2) * PLANE;
  #pragma unroll
  for (int i = 0; i < 2; ++i) {
    int g = tid + i * 256;           // 32 rows x 16 groups of 4 px
    int py = g >> 4, pxg = g & 15;
    int col = pxg * 4;
    int ybk = (py >> 3) * 8 + (col >> 3);
    int yoff = (py & 7) * 8 + (col & 7);
    float4 yv4 = *(const float4*)&Blk[ybk][yoff];
    float yv[4] = {yv4.x, yv4.y, yv4.z, yv4.w};

    int cy = py >> 1, cx = 2 * pxg;
    int cbk = 32 + (cy >> 3) * 4 + (cx >> 3);
    int coff = (cy & 7) * 8 + (cx & 7);
    float2 cbv = *(const float2*)&Blk[cbk][coff];
    float2 crv = *(const float2*)&Blk[cbk + 8][coff];
    float cb0 = __fadd_rn(cbv.x, -128.0f);
    float cb1 = __fadd_rn(cbv.y, -128.0f);
    float cr0 = __fadd_rn(crv.x, -128.0f);
    float cr1 = __fadd_rn(crv.y, -128.0f);
    float cb[4] = {cb0, cb0, cb1, cb1};
    float cr[4] = {cr0, cr0, cr1, cr1};

    float rr[4], gg[4], bb[4];
    #pragma unroll
    for (int j = 0; j < 4; ++j) {
      float R  = __fmaf_rn(cr[j], 1.402f, yv[j]);
      float G  = __fmaf_rn(cr[j], -0.714136f, __fmaf_rn(cb[j], -0.344136f, yv[j]));
      float Bv = __fmaf_rn(cb[j], 1.772f, yv[j]);
      R  = fminf(fmaxf(R,  0.0f), 255.0f);
      G  = fminf(fmaxf(G,  0.0f), 255.0f);
      Bv = fminf(fmaxf(Bv, 0.0f), 255.0f);
      rr[j] = __fdiv_rn(R,  255.0f);
      gg[j] = __fdiv_rn(G,  255.0f);
      bb[j] = __fdiv_rn(Bv, 255.0f);
    }
    size_t o = (size_t)(row0 + py) * WW + (col0 + col);
    *(float4*)(oR + o) = make_float4(rr[0], rr[1], rr[2], rr[3]);
    *(float4*)(oG + o) = make_float4(gg[0], gg[1], gg[2], gg[3]);
    *(float4*)(oB + o) = make_float4(bb[0], bb[1], bb[2], bb[3]);
  }
}

extern "C" void kernel_launch(void* const* d_in, const int* in_sizes, int n_in,
                              void* d_out, int out_size, void* d_ws, size_t ws_size,
                              hipStream_t stream) {
  (void)in_sizes; (void)n_in; (void)d_ws; (void)ws_size; (void)out_size;
  const float* x   = (const float*)d_in[0];
  const float* src = (const float*)d_in[1];
  float* out = (float*)d_out;

  diffjpeg_kernel<<<dim3(BATCH * 128), dim3(256), 0, stream>>>(x, src, out);
}